// Round 2
// baseline (556.735 us; speedup 1.0000x reference)
//
#include <hip/hip_runtime.h>
#include <hip/hip_bf16.h>

// MoE layer, routed top-2 implementation.
// N=4096 tokens, D=768, F=3072, E=8. All inputs fp32; compute in f16 MFMA
// (fp32 accumulate), gating in fp64 for exact top-2 selection.

#define N_TOK 4096
#define DIM   768
#define FDIM  3072
#define NEXP  8

typedef __attribute__((ext_vector_type(8))) _Float16 f16x8;
typedef __attribute__((ext_vector_type(4))) _Float16 f16x4;
typedef __attribute__((ext_vector_type(4))) float     f32x4;

__device__ __forceinline__ float gelu_exact(float v) {
    return 0.5f * v * (1.0f + erff(v * 0.7071067811865475f));
}

// async global->LDS, 16B per lane. Dest must be wave-uniform base + lane*16
// (our staging layout As[t>>2][(t&3)*8] is exactly linear in lane order).
__device__ __forceinline__ void gload_lds16(const _Float16* g, _Float16* l) {
    __builtin_amdgcn_global_load_lds(
        (const __attribute__((address_space(1))) void*)g,
        (__attribute__((address_space(3))) void*)l,
        16, 0, 0);
}

// ---------------- cast x (fp32 -> f16), vectorized ----------------
__global__ __launch_bounds__(256) void cast_x_kernel(const float* __restrict__ x,
                                                     _Float16* __restrict__ xh) {
    int i = blockIdx.x * 256 + threadIdx.x;   // one float4 per thread, grid sized exactly
    float4 v = ((const float4*)x)[i];
    f16x4 o;
    o[0] = (_Float16)v.x; o[1] = (_Float16)v.y;
    o[2] = (_Float16)v.z; o[3] = (_Float16)v.w;
    ((f16x4*)xh)[i] = o;
}

// ---------------- transpose + cast: fp32 [E][R][C] -> f16 [E][C][R] ----------------
__global__ __launch_bounds__(256) void transpose_cast_kernel(const float* __restrict__ in,
                                                             _Float16* __restrict__ out,
                                                             int R, int C) {
    const int e  = blockIdx.z;
    const size_t eoff = (size_t)e * R * C;
    const int c0 = blockIdx.x * 64;
    const int r0 = blockIdx.y * 64;
    __shared__ _Float16 tile[64][66];   // pitch 66 to soften bank conflicts
    const int t = threadIdx.x;
    #pragma unroll
    for (int it = 0; it < 4; it++) {
        int lin = it * 256 + t;
        int r  = lin >> 4;       // 0..63
        int c4 = lin & 15;       // float4 column group
        float4 v = *(const float4*)&in[eoff + (size_t)(r0 + r) * C + c0 + c4 * 4];
        tile[r][c4 * 4 + 0] = (_Float16)v.x;
        tile[r][c4 * 4 + 1] = (_Float16)v.y;
        tile[r][c4 * 4 + 2] = (_Float16)v.z;
        tile[r][c4 * 4 + 3] = (_Float16)v.w;
    }
    __syncthreads();
    #pragma unroll
    for (int it = 0; it < 4; it++) {
        int lin = it * 256 + t;
        int c  = lin >> 4;       // out row (= original column)
        int r4 = lin & 15;       // group of 4 original rows
        f16x4 o;
        #pragma unroll
        for (int j = 0; j < 4; j++) o[j] = tile[r4 * 4 + j][c];
        *(f16x4*)&out[eoff + (size_t)(c0 + c) * R + r0 + r4 * 4] = o;
    }
}

// ---------------- gating: fp64 logits, softmax, top-2, per-expert lists ----------------
__global__ __launch_bounds__(256) void gate_kernel(const float* __restrict__ x,
                                                   const float* __restrict__ gw,
                                                   const float* __restrict__ gb,
                                                   int* __restrict__ tok_list,
                                                   float* __restrict__ wt_list,
                                                   int* __restrict__ count) {
    const int gtid = blockIdx.x * 256 + threadIdx.x;
    const int n    = gtid >> 6;        // one wave per token
    const int lane = threadIdx.x & 63;
    if (n >= N_TOK) return;
    double part[NEXP];
    #pragma unroll
    for (int e = 0; e < NEXP; e++) part[e] = 0.0;
    for (int d = lane; d < DIM; d += 64) {
        float xv = x[n * DIM + d];
        const float* g = &gw[d * NEXP];
        #pragma unroll
        for (int e = 0; e < NEXP; e++) part[e] += (double)xv * (double)g[e];
    }
    #pragma unroll
    for (int e = 0; e < NEXP; e++) {
        double v = part[e];
        #pragma unroll
        for (int off = 32; off > 0; off >>= 1) v += __shfl_xor(v, off);
        part[e] = v + (double)gb[e];
    }
    if (lane == 0) {
        double mx = part[0];
        #pragma unroll
        for (int e = 1; e < NEXP; e++) mx = fmax(mx, part[e]);
        double ex[NEXP]; double s = 0.0;
        #pragma unroll
        for (int e = 0; e < NEXP; e++) { ex[e] = exp(part[e] - mx); s += ex[e]; }
        int i0 = 0;
        #pragma unroll
        for (int e = 1; e < NEXP; e++) if (ex[e] > ex[i0]) i0 = e;   // first-max tie-break, matches top_k
        int i1 = (i0 == 0) ? 1 : 0;
        #pragma unroll
        for (int e = 0; e < NEXP; e++) if (e != i0 && ex[e] > ex[i1]) i1 = e;
        float g0 = (float)(ex[i0] / s), g1 = (float)(ex[i1] / s);
        float dn = g0 + g1 + 1e-9f;
        float w0 = g0 / dn, w1 = g1 / dn;
        int s0 = atomicAdd(&count[i0], 1);
        tok_list[i0 * N_TOK + s0] = n;  wt_list[i0 * N_TOK + s0] = w0;
        int s1 = atomicAdd(&count[i1], 1);
        tok_list[i1 * N_TOK + s1] = n;  wt_list[i1 * N_TOK + s1] = w1;
    }
}

// ---------------- tiny prefix scan over 8 expert counts ----------------
__global__ void scan_kernel(const int* __restrict__ count, int* __restrict__ basep) {
    if (threadIdx.x == 0) {
        int s = 0;
        for (int e = 0; e < NEXP; e++) { basep[e] = s; s += count[e]; }
    }
}

// ---------------- GEMM1: h = gelu(x_gathered @ w1[e] + b1[e]) ----------------
// 128x128 tile, BK=32, 4 waves (2x2), 4x4 mfma_f32_16x16x32_f16 per wave.
// K-loop: 2-deep prefetch pipeline, 3-buffer LDS ring, counted vmcnt + raw
// s_barrier (one barrier per K-step). Safety: each wave's lgkmcnt(0)+barrier
// at the top of iteration t guarantees all reads of buffer b_{t-1} (== the
// STAGE target b_{t+2}) have landed in registers; vmcnt(4) guarantees every
// wave's tile-t stage loads completed before any wave ds_reads tile t.
__global__ __launch_bounds__(256) void mm1_kernel(const _Float16* __restrict__ xh,
                                                  const _Float16* __restrict__ w1t,
                                                  const float* __restrict__ bias1,
                                                  const int* __restrict__ tok_list,
                                                  const int* __restrict__ count,
                                                  const int* __restrict__ basep,
                                                  _Float16* __restrict__ h) {
    const int e    = blockIdx.y;
    const int cnt  = count[e];
    const int row0 = blockIdx.z * 128;
    if (row0 >= cnt) return;
    const int col0 = blockIdx.x * 128;
    const int t    = threadIdx.x;
    const int lane = t & 63;
    const int wv   = t >> 6;
    const int wy   = wv >> 1, wx = wv & 1;
    const int m_lane = lane & 15, quad = lane >> 4;

    __shared__ __align__(16) _Float16 As[3][128][32];
    __shared__ __align__(16) _Float16 Bs[3][128][32];

    const int srow = t >> 2;            // 0..63 staging row
    const int kin  = (t & 3) * 8;       // 8-elem k chunk

    int i0 = row0 + srow;      if (i0 > cnt - 1) i0 = cnt - 1;
    int i1 = row0 + 64 + srow; if (i1 > cnt - 1) i1 = cnt - 1;
    const int tokA0 = tok_list[e * N_TOK + i0];
    const int tokA1 = tok_list[e * N_TOK + i1];
    const _Float16* pa0 = xh + (size_t)tokA0 * DIM + kin;
    const _Float16* pa1 = xh + (size_t)tokA1 * DIM + kin;
    const _Float16* pb0 = w1t + (size_t)e * FDIM * DIM + (size_t)(col0 + srow) * DIM + kin;
    const _Float16* pb1 = pb0 + (size_t)64 * DIM;

    f32x4 acc[4][4];
    #pragma unroll
    for (int i = 0; i < 4; i++)
        #pragma unroll
        for (int j = 0; j < 4; j++)
            acc[i][j] = (f32x4){0.f, 0.f, 0.f, 0.f};

    const int NT = DIM / 32;   // 24

    // drain all address-setup loads so the vmcnt ledger below is exact
    asm volatile("s_waitcnt vmcnt(0)" ::: "memory");
    // prologue: stage tiles 0 and 1 (4 gload_lds instructions each)
    gload_lds16(pa0, &As[0][srow][kin]);
    gload_lds16(pa1, &As[0][64 + srow][kin]);
    gload_lds16(pb0, &Bs[0][srow][kin]);
    gload_lds16(pb1, &Bs[0][64 + srow][kin]);
    gload_lds16(pa0 + 32, &As[1][srow][kin]);
    gload_lds16(pa1 + 32, &As[1][64 + srow][kin]);
    gload_lds16(pb0 + 32, &Bs[1][srow][kin]);
    gload_lds16(pb1 + 32, &Bs[1][64 + srow][kin]);

    int cur = 0;
    for (int ti = 0; ti < NT; ++ti) {
        // own tile-ti stages done (<=4 outstanding = tile ti+1's), own LDS reads landed
        if (ti == NT - 1) asm volatile("s_waitcnt vmcnt(0) lgkmcnt(0)" ::: "memory");
        else              asm volatile("s_waitcnt vmcnt(4) lgkmcnt(0)" ::: "memory");
        __builtin_amdgcn_s_barrier();
        asm volatile("" ::: "memory");
        // issue prefetch of tile ti+2 into ring slot (cur+2)%3
        if (ti + 2 < NT) {
            int nb = cur + 2; if (nb >= 3) nb -= 3;
            int kk = (ti + 2) * 32;
            gload_lds16(pa0 + kk, &As[nb][srow][kin]);
            gload_lds16(pa1 + kk, &As[nb][64 + srow][kin]);
            gload_lds16(pb0 + kk, &Bs[nb][srow][kin]);
            gload_lds16(pb1 + kk, &Bs[nb][64 + srow][kin]);
        }
        f16x8 af[4], bf[4];
        #pragma unroll
        for (int i = 0; i < 4; i++)
            af[i] = *(const f16x8*)&As[cur][wy * 64 + i * 16 + m_lane][quad * 8];
        #pragma unroll
        for (int j = 0; j < 4; j++)
            bf[j] = *(const f16x8*)&Bs[cur][wx * 64 + j * 16 + m_lane][quad * 8];
        #pragma unroll
        for (int i = 0; i < 4; i++)
            #pragma unroll
            for (int j = 0; j < 4; j++)
                acc[i][j] = __builtin_amdgcn_mfma_f32_16x16x32_f16(af[i], bf[j], acc[i][j], 0, 0, 0);
        cur = cur + 1; if (cur >= 3) cur = 0;
    }

    const int hbase = basep[e];
    #pragma unroll
    for (int i = 0; i < 4; i++) {
        #pragma unroll
        for (int r = 0; r < 4; r++) {
            int rl = wy * 64 + i * 16 + quad * 4 + r;   // C/D: row=(lane>>4)*4+reg
            int gr = row0 + rl;
            if (gr < cnt) {
                _Float16* hrow = h + (size_t)(hbase + gr) * FDIM;
                #pragma unroll
                for (int j = 0; j < 4; j++) {
                    int c = col0 + wx * 64 + j * 16 + m_lane;   // C/D: col=lane&15
                    float v = acc[i][j][r] + bias1[e * FDIM + c];
                    hrow[c] = (_Float16)gelu_exact(v);
                }
            }
        }
    }
}

// ---------------- GEMM2: out += gate_w * (h @ w2[e] + b2[e]) ----------------
// Split-K=2 (K=3072 -> 2x1536) to double live blocks (384 -> 768, 3/CU);
// output is atomicAdd-combined anyway so split-K is free; bias added by ks==0.
// Same 2-deep prefetch / 3-buffer ring / counted-vmcnt K-loop as mm1.
__global__ __launch_bounds__(256) void mm2_kernel(const _Float16* __restrict__ h,
                                                  const _Float16* __restrict__ w2t,
                                                  const float* __restrict__ bias2,
                                                  const int* __restrict__ tok_list,
                                                  const float* __restrict__ wt_list,
                                                  const int* __restrict__ count,
                                                  const int* __restrict__ basep,
                                                  float* __restrict__ out) {
    const int e    = blockIdx.y >> 1;
    const int ks   = blockIdx.y & 1;
    const int cnt  = count[e];
    const int row0 = blockIdx.z * 128;
    if (row0 >= cnt) return;
    const int col0 = blockIdx.x * 128;
    const int t    = threadIdx.x;
    const int lane = t & 63;
    const int wv   = t >> 6;
    const int wy   = wv >> 1, wx = wv & 1;
    const int m_lane = lane & 15, quad = lane >> 4;

    __shared__ __align__(16) _Float16 As[3][128][32];
    __shared__ __align__(16) _Float16 Bs[3][128][32];

    const int srow = t >> 2;
    const int kin  = (t & 3) * 8;

    const int hbase = basep[e];
    int i0 = row0 + srow;      if (i0 > cnt - 1) i0 = cnt - 1;
    int i1 = row0 + 64 + srow; if (i1 > cnt - 1) i1 = cnt - 1;
    const size_t koff = (size_t)ks * (FDIM / 2);
    const _Float16* pa0 = h + (size_t)(hbase + i0) * FDIM + koff + kin;
    const _Float16* pa1 = h + (size_t)(hbase + i1) * FDIM + koff + kin;
    const _Float16* pb0 = w2t + (size_t)e * DIM * FDIM + (size_t)(col0 + srow) * FDIM + koff + kin;
    const _Float16* pb1 = pb0 + (size_t)64 * FDIM;

    f32x4 acc[4][4];
    #pragma unroll
    for (int i = 0; i < 4; i++)
        #pragma unroll
        for (int j = 0; j < 4; j++)
            acc[i][j] = (f32x4){0.f, 0.f, 0.f, 0.f};

    const int NT = (FDIM / 2) / 32;   // 48

    asm volatile("s_waitcnt vmcnt(0)" ::: "memory");
    gload_lds16(pa0, &As[0][srow][kin]);
    gload_lds16(pa1, &As[0][64 + srow][kin]);
    gload_lds16(pb0, &Bs[0][srow][kin]);
    gload_lds16(pb1, &Bs[0][64 + srow][kin]);
    gload_lds16(pa0 + 32, &As[1][srow][kin]);
    gload_lds16(pa1 + 32, &As[1][64 + srow][kin]);
    gload_lds16(pb0 + 32, &Bs[1][srow][kin]);
    gload_lds16(pb1 + 32, &Bs[1][64 + srow][kin]);

    int cur = 0;
    for (int ti = 0; ti < NT; ++ti) {
        if (ti == NT - 1) asm volatile("s_waitcnt vmcnt(0) lgkmcnt(0)" ::: "memory");
        else              asm volatile("s_waitcnt vmcnt(4) lgkmcnt(0)" ::: "memory");
        __builtin_amdgcn_s_barrier();
        asm volatile("" ::: "memory");
        if (ti + 2 < NT) {
            int nb = cur + 2; if (nb >= 3) nb -= 3;
            int kk = (ti + 2) * 32;
            gload_lds16(pa0 + kk, &As[nb][srow][kin]);
            gload_lds16(pa1 + kk, &As[nb][64 + srow][kin]);
            gload_lds16(pb0 + kk, &Bs[nb][srow][kin]);
            gload_lds16(pb1 + kk, &Bs[nb][64 + srow][kin]);
        }
        f16x8 af[4], bf[4];
        #pragma unroll
        for (int i = 0; i < 4; i++)
            af[i] = *(const f16x8*)&As[cur][wy * 64 + i * 16 + m_lane][quad * 8];
        #pragma unroll
        for (int j = 0; j < 4; j++)
            bf[j] = *(const f16x8*)&Bs[cur][wx * 64 + j * 16 + m_lane][quad * 8];
        #pragma unroll
        for (int i = 0; i < 4; i++)
            #pragma unroll
            for (int j = 0; j < 4; j++)
                acc[i][j] = __builtin_amdgcn_mfma_f32_16x16x32_f16(af[i], bf[j], acc[i][j], 0, 0, 0);
        cur = cur + 1; if (cur >= 3) cur = 0;
    }

    #pragma unroll
    for (int i = 0; i < 4; i++) {
        #pragma unroll
        for (int r = 0; r < 4; r++) {
            int rl = wy * 64 + i * 16 + quad * 4 + r;
            int gr = row0 + rl;
            if (gr < cnt) {
                int tok   = tok_list[e * N_TOK + gr];
                float wgt = wt_list[e * N_TOK + gr];
                float* orow = out + (size_t)tok * DIM;
                #pragma unroll
                for (int j = 0; j < 4; j++) {
                    int c = col0 + wx * 64 + j * 16 + m_lane;
                    float v = acc[i][j][r] + ((ks == 0) ? bias2[e * DIM + c] : 0.f);
                    atomicAdd(&orow[c], wgt * v);
                }
            }
        }
    }
}

extern "C" void kernel_launch(void* const* d_in, const int* in_sizes, int n_in,
                              void* d_out, int out_size, void* d_ws, size_t ws_size,
                              hipStream_t stream) {
    const float* x  = (const float*)d_in[0];
    const float* gw = (const float*)d_in[1];
    const float* gb = (const float*)d_in[2];
    const float* w1 = (const float*)d_in[3];
    const float* b1 = (const float*)d_in[4];
    const float* w2 = (const float*)d_in[5];
    const float* b2 = (const float*)d_in[6];
    float* out = (float*)d_out;

    // workspace layout (all 16B-aligned); total ~132.4 MB
    char* ws = (char*)d_ws;
    _Float16* xh   = (_Float16*)ws;                                    // 4096*768
    _Float16* w1t  = xh  + (size_t)N_TOK * DIM;                        // [E][F][D]
    _Float16* w2t  = w1t + (size_t)NEXP * FDIM * DIM;                  // [E][D][F]
    _Float16* hbuf = w2t + (size_t)NEXP * DIM * FDIM;                  // [2N][F] compact slots
    int*   tok_list = (int*)(hbuf + (size_t)2 * N_TOK * FDIM);         // [E][N]
    float* wt_list  = (float*)(tok_list + NEXP * N_TOK);               // [E][N]
    int*   count    = (int*)(wt_list + NEXP * N_TOK);                  // [E]
    int*   basep    = count + 8;                                       // [E]

    hipMemsetAsync(count, 0, 64, stream);                 // count + base
    hipMemsetAsync(out, 0, (size_t)out_size * sizeof(float), stream);

    cast_x_kernel<<<dim3(N_TOK * DIM / 4 / 256), 256, 0, stream>>>(x, xh);
    // w1: [E][768][3072] -> w1t [E][3072][768]
    transpose_cast_kernel<<<dim3(FDIM / 64, DIM / 64, NEXP), 256, 0, stream>>>(w1, w1t, DIM, FDIM);
    // w2: [E][3072][768] -> w2t [E][768][3072]
    transpose_cast_kernel<<<dim3(DIM / 64, FDIM / 64, NEXP), 256, 0, stream>>>(w2, w2t, FDIM, DIM);
    gate_kernel<<<dim3(N_TOK / 4), 256, 0, stream>>>(x, gw, gb, tok_list, wt_list, count);
    scan_kernel<<<1, 64, 0, stream>>>(count, basep);
    // grid: (cols, experts, rowblocks) -> live blocks are a dense prefix
    mm1_kernel<<<dim3(FDIM / 128, NEXP, N_TOK / 128), 256, 0, stream>>>(
        xh, w1t, b1, tok_list, count, basep, hbuf);
    // mm2: blockIdx.y = expert*2 + ksplit
    mm2_kernel<<<dim3(DIM / 128, NEXP * 2, N_TOK / 128), 256, 0, stream>>>(
        hbuf, w2t, b2, tok_list, wt_list, count, basep, out);
}

// Round 3
// 531.801 us; speedup vs baseline: 1.0469x; 1.0469x over previous
//
#include <hip/hip_runtime.h>
#include <hip/hip_bf16.h>

// MoE layer, routed top-2 implementation.
// N=4096 tokens, D=768, F=3072, E=8. All inputs fp32; compute in f16 MFMA
// (fp32 accumulate), gating in fp64 for exact top-2 selection.

#define N_TOK 4096
#define DIM   768
#define FDIM  3072
#define NEXP  8

typedef __attribute__((ext_vector_type(8))) _Float16 f16x8;
typedef __attribute__((ext_vector_type(4))) _Float16 f16x4;
typedef __attribute__((ext_vector_type(4))) float     f32x4;

__device__ __forceinline__ float gelu_exact(float v) {
    return 0.5f * v * (1.0f + erff(v * 0.7071067811865475f));
}

// async global->LDS, 16B per lane. Dest must be wave-uniform base + lane*16
// (our staging layout As[t>>2][(t&3)*8] is exactly linear in lane order).
__device__ __forceinline__ void gload_lds16(const _Float16* g, _Float16* l) {
    __builtin_amdgcn_global_load_lds(
        (const __attribute__((address_space(1))) void*)g,
        (__attribute__((address_space(3))) void*)l,
        16, 0, 0);
}

// ---------------- cast x (fp32 -> f16), vectorized ----------------
__global__ __launch_bounds__(256) void cast_x_kernel(const float* __restrict__ x,
                                                     _Float16* __restrict__ xh) {
    int i = blockIdx.x * 256 + threadIdx.x;   // one float4 per thread, grid sized exactly
    float4 v = ((const float4*)x)[i];
    f16x4 o;
    o[0] = (_Float16)v.x; o[1] = (_Float16)v.y;
    o[2] = (_Float16)v.z; o[3] = (_Float16)v.w;
    ((f16x4*)xh)[i] = o;
}

// ---------------- merged transpose + cast for w1 and w2 ----------------
// fp32 [E][R][C] -> f16 [E][C][R]; blockIdx.y: 0..7 = w1 experts, 8..15 = w2.
__global__ __launch_bounds__(256) void transpose_cast2_kernel(const float* __restrict__ w1,
                                                              const float* __restrict__ w2,
                                                              _Float16* __restrict__ w1t,
                                                              _Float16* __restrict__ w2t) {
    const int z     = blockIdx.y;
    const int which = z >> 3;
    const int e     = z & 7;
    const float* in; _Float16* out; int R, C, tx, ty;
    if (which == 0) { in = w1; out = w1t; R = DIM;  C = FDIM; tx = blockIdx.x % (FDIM / 64); ty = blockIdx.x / (FDIM / 64); }
    else            { in = w2; out = w2t; R = FDIM; C = DIM;  tx = blockIdx.x % (DIM  / 64); ty = blockIdx.x / (DIM  / 64); }
    const size_t eoff = (size_t)e * R * C;
    const int c0 = tx * 64;
    const int r0 = ty * 64;
    __shared__ _Float16 tile[64][66];   // pitch 66 to soften bank conflicts
    const int t = threadIdx.x;
    #pragma unroll
    for (int it = 0; it < 4; it++) {
        int lin = it * 256 + t;
        int r  = lin >> 4;       // 0..63
        int c4 = lin & 15;       // float4 column group
        float4 v = *(const float4*)&in[eoff + (size_t)(r0 + r) * C + c0 + c4 * 4];
        tile[r][c4 * 4 + 0] = (_Float16)v.x;
        tile[r][c4 * 4 + 1] = (_Float16)v.y;
        tile[r][c4 * 4 + 2] = (_Float16)v.z;
        tile[r][c4 * 4 + 3] = (_Float16)v.w;
    }
    __syncthreads();
    #pragma unroll
    for (int it = 0; it < 4; it++) {
        int lin = it * 256 + t;
        int c  = lin >> 4;       // out row (= original column)
        int r4 = lin & 15;       // group of 4 original rows
        f16x4 o;
        #pragma unroll
        for (int j = 0; j < 4; j++) o[j] = tile[r4 * 4 + j][c];
        *(f16x4*)&out[eoff + (size_t)(c0 + c) * R + r0 + r4 * 4] = o;
    }
}

// ---------------- gating: fp64 logits, softmax, top-2, per-expert lists ----------------
__global__ __launch_bounds__(256) void gate_kernel(const float* __restrict__ x,
                                                   const float* __restrict__ gw,
                                                   const float* __restrict__ gb,
                                                   int* __restrict__ tok_list,
                                                   float* __restrict__ wt_list,
                                                   int* __restrict__ count) {
    const int gtid = blockIdx.x * 256 + threadIdx.x;
    const int n    = gtid >> 6;        // one wave per token
    const int lane = threadIdx.x & 63;
    if (n >= N_TOK) return;
    double part[NEXP];
    #pragma unroll
    for (int e = 0; e < NEXP; e++) part[e] = 0.0;
    for (int d = lane; d < DIM; d += 64) {
        float xv = x[n * DIM + d];
        const float* g = &gw[d * NEXP];
        #pragma unroll
        for (int e = 0; e < NEXP; e++) part[e] += (double)xv * (double)g[e];
    }
    #pragma unroll
    for (int e = 0; e < NEXP; e++) {
        double v = part[e];
        #pragma unroll
        for (int off = 32; off > 0; off >>= 1) v += __shfl_xor(v, off);
        part[e] = v + (double)gb[e];
    }
    if (lane == 0) {
        double mx = part[0];
        #pragma unroll
        for (int e = 1; e < NEXP; e++) mx = fmax(mx, part[e]);
        double ex[NEXP]; double s = 0.0;
        #pragma unroll
        for (int e = 0; e < NEXP; e++) { ex[e] = exp(part[e] - mx); s += ex[e]; }
        int i0 = 0;
        #pragma unroll
        for (int e = 1; e < NEXP; e++) if (ex[e] > ex[i0]) i0 = e;   // first-max tie-break, matches top_k
        int i1 = (i0 == 0) ? 1 : 0;
        #pragma unroll
        for (int e = 0; e < NEXP; e++) if (e != i0 && ex[e] > ex[i1]) i1 = e;
        float g0 = (float)(ex[i0] / s), g1 = (float)(ex[i1] / s);
        float dn = g0 + g1 + 1e-9f;
        float w0 = g0 / dn, w1 = g1 / dn;
        int s0 = atomicAdd(&count[i0], 1);
        tok_list[i0 * N_TOK + s0] = n;  wt_list[i0 * N_TOK + s0] = w0;
        int s1 = atomicAdd(&count[i1], 1);
        tok_list[i1 * N_TOK + s1] = n;  wt_list[i1 * N_TOK + s1] = w1;
    }
}

// ---------------- tiny prefix scan over 8 expert counts ----------------
__global__ void scan_kernel(const int* __restrict__ count, int* __restrict__ basep) {
    if (threadIdx.x == 0) {
        int s = 0;
        for (int e = 0; e < NEXP; e++) { basep[e] = s; s += count[e]; }
    }
}

// ---------------- GEMM1: h = gelu(x_gathered @ w1[e] + b1[e]) ----------------
// 128x128 tile, BK=32, 4 waves (2x2), 4x4 mfma_f32_16x16x32_f16 per wave.
// 2-phase double-buffer (catalog T3-minimum): issue STAGE(t+1) into buf^1
// BEFORE consuming buf, one __syncthreads per step. No inline asm — the
// implicit vmcnt(0)+lgkmcnt(0) drain at the barrier keeps the swap race-free
// while the t+1 loads overlap the ds_read+MFMA phase of tile t.
__global__ __launch_bounds__(256) void mm1_kernel(const _Float16* __restrict__ xh,
                                                  const _Float16* __restrict__ w1t,
                                                  const float* __restrict__ bias1,
                                                  const int* __restrict__ tok_list,
                                                  const int* __restrict__ count,
                                                  const int* __restrict__ basep,
                                                  _Float16* __restrict__ h) {
    const int e    = blockIdx.y;
    const int cnt  = count[e];
    const int row0 = blockIdx.z * 128;
    if (row0 >= cnt) return;
    const int col0 = blockIdx.x * 128;
    const int t    = threadIdx.x;
    const int lane = t & 63;
    const int wv   = t >> 6;
    const int wy   = wv >> 1, wx = wv & 1;
    const int m_lane = lane & 15, quad = lane >> 4;

    __shared__ __align__(16) _Float16 As[2][128][32];
    __shared__ __align__(16) _Float16 Bs[2][128][32];

    const int srow = t >> 2;            // 0..63 staging row
    const int kin  = (t & 3) * 8;       // 8-elem k chunk

    int i0 = row0 + srow;      if (i0 > cnt - 1) i0 = cnt - 1;
    int i1 = row0 + 64 + srow; if (i1 > cnt - 1) i1 = cnt - 1;
    const int tokA0 = tok_list[e * N_TOK + i0];
    const int tokA1 = tok_list[e * N_TOK + i1];
    const _Float16* pa0 = xh + (size_t)tokA0 * DIM + kin;
    const _Float16* pa1 = xh + (size_t)tokA1 * DIM + kin;
    const _Float16* pb0 = w1t + (size_t)e * FDIM * DIM + (size_t)(col0 + srow) * DIM + kin;
    const _Float16* pb1 = pb0 + (size_t)64 * DIM;

    f32x4 acc[4][4];
    #pragma unroll
    for (int i = 0; i < 4; i++)
        #pragma unroll
        for (int j = 0; j < 4; j++)
            acc[i][j] = (f32x4){0.f, 0.f, 0.f, 0.f};

    const int NT = DIM / 32;   // 24

    // prologue: stage tile 0 into buffer 0
    gload_lds16(pa0, &As[0][srow][kin]);
    gload_lds16(pa1, &As[0][64 + srow][kin]);
    gload_lds16(pb0, &Bs[0][srow][kin]);
    gload_lds16(pb1, &Bs[0][64 + srow][kin]);
    __syncthreads();

    int cur = 0;
    for (int ti = 0; ti < NT; ++ti) {
        if (ti + 1 < NT) {                  // issue next-tile loads first (overlap)
            int kk = (ti + 1) * 32;
            int nb = cur ^ 1;
            gload_lds16(pa0 + kk, &As[nb][srow][kin]);
            gload_lds16(pa1 + kk, &As[nb][64 + srow][kin]);
            gload_lds16(pb0 + kk, &Bs[nb][srow][kin]);
            gload_lds16(pb1 + kk, &Bs[nb][64 + srow][kin]);
        }
        f16x8 af[4], bf[4];
        #pragma unroll
        for (int i = 0; i < 4; i++)
            af[i] = *(const f16x8*)&As[cur][wy * 64 + i * 16 + m_lane][quad * 8];
        #pragma unroll
        for (int j = 0; j < 4; j++)
            bf[j] = *(const f16x8*)&Bs[cur][wx * 64 + j * 16 + m_lane][quad * 8];
        #pragma unroll
        for (int i = 0; i < 4; i++)
            #pragma unroll
            for (int j = 0; j < 4; j++)
                acc[i][j] = __builtin_amdgcn_mfma_f32_16x16x32_f16(af[i], bf[j], acc[i][j], 0, 0, 0);
        __syncthreads();                    // drain own loads + barrier -> swap safe
        cur ^= 1;
    }

    const int hbase = basep[e];
    #pragma unroll
    for (int i = 0; i < 4; i++) {
        #pragma unroll
        for (int r = 0; r < 4; r++) {
            int rl = wy * 64 + i * 16 + quad * 4 + r;   // C/D: row=(lane>>4)*4+reg
            int gr = row0 + rl;
            if (gr < cnt) {
                _Float16* hrow = h + (size_t)(hbase + gr) * FDIM;
                #pragma unroll
                for (int j = 0; j < 4; j++) {
                    int c = col0 + wx * 64 + j * 16 + m_lane;   // C/D: col=lane&15
                    float v = acc[i][j][r] + bias1[e * FDIM + c];
                    hrow[c] = (_Float16)gelu_exact(v);
                }
            }
        }
    }
}

// ---------------- GEMM2: out += gate_w * (h @ w2[e] + b2[e]) ----------------
// Split-K=2 (K=3072 -> 2x1536): grid 384 -> 768 live blocks (3/CU) to fix
// starvation; output is atomicAdd-combined anyway, bias added by ks==0 only.
// Same simple 2-phase double-buffer loop as mm1 (no inline asm).
__global__ __launch_bounds__(256) void mm2_kernel(const _Float16* __restrict__ h,
                                                  const _Float16* __restrict__ w2t,
                                                  const float* __restrict__ bias2,
                                                  const int* __restrict__ tok_list,
                                                  const float* __restrict__ wt_list,
                                                  const int* __restrict__ count,
                                                  const int* __restrict__ basep,
                                                  float* __restrict__ out) {
    const int e    = blockIdx.y >> 1;
    const int ks   = blockIdx.y & 1;
    const int cnt  = count[e];
    const int row0 = blockIdx.z * 128;
    if (row0 >= cnt) return;
    const int col0 = blockIdx.x * 128;
    const int t    = threadIdx.x;
    const int lane = t & 63;
    const int wv   = t >> 6;
    const int wy   = wv >> 1, wx = wv & 1;
    const int m_lane = lane & 15, quad = lane >> 4;

    __shared__ __align__(16) _Float16 As[2][128][32];
    __shared__ __align__(16) _Float16 Bs[2][128][32];

    const int srow = t >> 2;
    const int kin  = (t & 3) * 8;

    const int hbase = basep[e];
    int i0 = row0 + srow;      if (i0 > cnt - 1) i0 = cnt - 1;
    int i1 = row0 + 64 + srow; if (i1 > cnt - 1) i1 = cnt - 1;
    const size_t koff = (size_t)ks * (FDIM / 2);
    const _Float16* pa0 = h + (size_t)(hbase + i0) * FDIM + koff + kin;
    const _Float16* pa1 = h + (size_t)(hbase + i1) * FDIM + koff + kin;
    const _Float16* pb0 = w2t + (size_t)e * DIM * FDIM + (size_t)(col0 + srow) * FDIM + koff + kin;
    const _Float16* pb1 = pb0 + (size_t)64 * FDIM;

    f32x4 acc[4][4];
    #pragma unroll
    for (int i = 0; i < 4; i++)
        #pragma unroll
        for (int j = 0; j < 4; j++)
            acc[i][j] = (f32x4){0.f, 0.f, 0.f, 0.f};

    const int NT = (FDIM / 2) / 32;   // 48

    gload_lds16(pa0, &As[0][srow][kin]);
    gload_lds16(pa1, &As[0][64 + srow][kin]);
    gload_lds16(pb0, &Bs[0][srow][kin]);
    gload_lds16(pb1, &Bs[0][64 + srow][kin]);
    __syncthreads();

    int cur = 0;
    for (int ti = 0; ti < NT; ++ti) {
        if (ti + 1 < NT) {
            int kk = (ti + 1) * 32;
            int nb = cur ^ 1;
            gload_lds16(pa0 + kk, &As[nb][srow][kin]);
            gload_lds16(pa1 + kk, &As[nb][64 + srow][kin]);
            gload_lds16(pb0 + kk, &Bs[nb][srow][kin]);
            gload_lds16(pb1 + kk, &Bs[nb][64 + srow][kin]);
        }
        f16x8 af[4], bf[4];
        #pragma unroll
        for (int i = 0; i < 4; i++)
            af[i] = *(const f16x8*)&As[cur][wy * 64 + i * 16 + m_lane][quad * 8];
        #pragma unroll
        for (int j = 0; j < 4; j++)
            bf[j] = *(const f16x8*)&Bs[cur][wx * 64 + j * 16 + m_lane][quad * 8];
        #pragma unroll
        for (int i = 0; i < 4; i++)
            #pragma unroll
            for (int j = 0; j < 4; j++)
                acc[i][j] = __builtin_amdgcn_mfma_f32_16x16x32_f16(af[i], bf[j], acc[i][j], 0, 0, 0);
        __syncthreads();
        cur ^= 1;
    }

    #pragma unroll
    for (int i = 0; i < 4; i++) {
        #pragma unroll
        for (int r = 0; r < 4; r++) {
            int rl = wy * 64 + i * 16 + quad * 4 + r;
            int gr = row0 + rl;
            if (gr < cnt) {
                int tok   = tok_list[e * N_TOK + gr];
                float wgt = wt_list[e * N_TOK + gr];
                float* orow = out + (size_t)tok * DIM;
                #pragma unroll
                for (int j = 0; j < 4; j++) {
                    int c = col0 + wx * 64 + j * 16 + m_lane;
                    float v = acc[i][j][r] + ((ks == 0) ? bias2[e * DIM + c] : 0.f);
                    atomicAdd(&orow[c], wgt * v);
                }
            }
        }
    }
}

extern "C" void kernel_launch(void* const* d_in, const int* in_sizes, int n_in,
                              void* d_out, int out_size, void* d_ws, size_t ws_size,
                              hipStream_t stream) {
    const float* x  = (const float*)d_in[0];
    const float* gw = (const float*)d_in[1];
    const float* gb = (const float*)d_in[2];
    const float* w1 = (const float*)d_in[3];
    const float* b1 = (const float*)d_in[4];
    const float* w2 = (const float*)d_in[5];
    const float* b2 = (const float*)d_in[6];
    float* out = (float*)d_out;

    // workspace layout (all 16B-aligned); total ~132.4 MB
    char* ws = (char*)d_ws;
    _Float16* xh   = (_Float16*)ws;                                    // 4096*768
    _Float16* w1t  = xh  + (size_t)N_TOK * DIM;                        // [E][F][D]
    _Float16* w2t  = w1t + (size_t)NEXP * FDIM * DIM;                  // [E][D][F]
    _Float16* hbuf = w2t + (size_t)NEXP * DIM * FDIM;                  // [2N][F] compact slots
    int*   tok_list = (int*)(hbuf + (size_t)2 * N_TOK * FDIM);         // [E][N]
    float* wt_list  = (float*)(tok_list + NEXP * N_TOK);               // [E][N]
    int*   count    = (int*)(wt_list + NEXP * N_TOK);                  // [E]
    int*   basep    = count + 8;                                       // [E]

    hipMemsetAsync(count, 0, 64, stream);                 // count + base
    hipMemsetAsync(out, 0, (size_t)out_size * sizeof(float), stream);

    cast_x_kernel<<<dim3(N_TOK * DIM / 4 / 256), 256, 0, stream>>>(x, xh);
    // w1: [E][768][3072] -> w1t [E][3072][768]; w2: [E][3072][768] -> w2t [E][768][3072]
    transpose_cast2_kernel<<<dim3(576, 16), 256, 0, stream>>>(w1, w2, w1t, w2t);
    gate_kernel<<<dim3(N_TOK / 4), 256, 0, stream>>>(x, gw, gb, tok_list, wt_list, count);
    scan_kernel<<<1, 64, 0, stream>>>(count, basep);
    // grid: (cols, experts, rowblocks) -> live blocks are a dense prefix
    mm1_kernel<<<dim3(FDIM / 128, NEXP, N_TOK / 128), 256, 0, stream>>>(
        xh, w1t, b1, tok_list, count, basep, hbuf);
    // mm2: blockIdx.y = expert*2 + ksplit
    mm2_kernel<<<dim3(DIM / 128, NEXP * 2, N_TOK / 128), 256, 0, stream>>>(
        hbuf, w2t, b2, tok_list, wt_list, count, basep, out);
}

// Round 4
// 506.932 us; speedup vs baseline: 1.0982x; 1.0491x over previous
//
#include <hip/hip_runtime.h>
#include <hip/hip_bf16.h>

// MoE layer, routed top-2 implementation.
// N=4096 tokens, D=768, F=3072, E=8. All inputs fp32; compute in f16 MFMA
// (fp32 accumulate), gating in fp64 for exact top-2 selection.

#define N_TOK 4096
#define DIM   768
#define FDIM  3072
#define NEXP  8

typedef __attribute__((ext_vector_type(8))) _Float16 f16x8;
typedef __attribute__((ext_vector_type(4))) _Float16 f16x4;
typedef __attribute__((ext_vector_type(4))) float     f32x4;

__device__ __forceinline__ float gelu_exact(float v) {
    return 0.5f * v * (1.0f + erff(v * 0.7071067811865475f));
}

// async global->LDS, 16B per lane. Dest must be wave-uniform base + lane*16.
__device__ __forceinline__ void gload_lds16(const _Float16* g, _Float16* l) {
    __builtin_amdgcn_global_load_lds(
        (const __attribute__((address_space(1))) void*)g,
        (__attribute__((address_space(3))) void*)l,
        16, 0, 0);
}

// ---------------- cast x (fp32 -> f16), vectorized ----------------
__global__ __launch_bounds__(256) void cast_x_kernel(const float* __restrict__ x,
                                                     _Float16* __restrict__ xh) {
    int i = blockIdx.x * 256 + threadIdx.x;   // one float4 per thread, grid sized exactly
    float4 v = ((const float4*)x)[i];
    f16x4 o;
    o[0] = (_Float16)v.x; o[1] = (_Float16)v.y;
    o[2] = (_Float16)v.z; o[3] = (_Float16)v.w;
    ((f16x4*)xh)[i] = o;
}

// ---------------- merged transpose + cast for w1 and w2 ----------------
// fp32 [E][R][C] -> f16 [E][C][R]; blockIdx.y: 0..7 = w1 experts, 8..15 = w2.
__global__ __launch_bounds__(256) void transpose_cast2_kernel(const float* __restrict__ w1,
                                                              const float* __restrict__ w2,
                                                              _Float16* __restrict__ w1t,
                                                              _Float16* __restrict__ w2t) {
    const int z     = blockIdx.y;
    const int which = z >> 3;
    const int e     = z & 7;
    const float* in; _Float16* out; int R, C, tx, ty;
    if (which == 0) { in = w1; out = w1t; R = DIM;  C = FDIM; tx = blockIdx.x % (FDIM / 64); ty = blockIdx.x / (FDIM / 64); }
    else            { in = w2; out = w2t; R = FDIM; C = DIM;  tx = blockIdx.x % (DIM  / 64); ty = blockIdx.x / (DIM  / 64); }
    const size_t eoff = (size_t)e * R * C;
    const int c0 = tx * 64;
    const int r0 = ty * 64;
    __shared__ _Float16 tile[64][66];   // pitch 66 to soften bank conflicts
    const int t = threadIdx.x;
    #pragma unroll
    for (int it = 0; it < 4; it++) {
        int lin = it * 256 + t;
        int r  = lin >> 4;       // 0..63
        int c4 = lin & 15;       // float4 column group
        float4 v = *(const float4*)&in[eoff + (size_t)(r0 + r) * C + c0 + c4 * 4];
        tile[r][c4 * 4 + 0] = (_Float16)v.x;
        tile[r][c4 * 4 + 1] = (_Float16)v.y;
        tile[r][c4 * 4 + 2] = (_Float16)v.z;
        tile[r][c4 * 4 + 3] = (_Float16)v.w;
    }
    __syncthreads();
    #pragma unroll
    for (int it = 0; it < 4; it++) {
        int lin = it * 256 + t;
        int c  = lin >> 4;       // out row (= original column)
        int r4 = lin & 15;       // group of 4 original rows
        f16x4 o;
        #pragma unroll
        for (int j = 0; j < 4; j++) o[j] = tile[r4 * 4 + j][c];
        *(f16x4*)&out[eoff + (size_t)(c0 + c) * R + r0 + r4 * 4] = o;
    }
}

// ---------------- gating: fp64 logits, softmax, top-2, per-expert lists ----------------
__global__ __launch_bounds__(256) void gate_kernel(const float* __restrict__ x,
                                                   const float* __restrict__ gw,
                                                   const float* __restrict__ gb,
                                                   int* __restrict__ tok_list,
                                                   float* __restrict__ wt_list,
                                                   int* __restrict__ count) {
    const int gtid = blockIdx.x * 256 + threadIdx.x;
    const int n    = gtid >> 6;        // one wave per token
    const int lane = threadIdx.x & 63;
    if (n >= N_TOK) return;
    double part[NEXP];
    #pragma unroll
    for (int e = 0; e < NEXP; e++) part[e] = 0.0;
    for (int d = lane; d < DIM; d += 64) {
        float xv = x[n * DIM + d];
        const float* g = &gw[d * NEXP];
        #pragma unroll
        for (int e = 0; e < NEXP; e++) part[e] += (double)xv * (double)g[e];
    }
    #pragma unroll
    for (int e = 0; e < NEXP; e++) {
        double v = part[e];
        #pragma unroll
        for (int off = 32; off > 0; off >>= 1) v += __shfl_xor(v, off);
        part[e] = v + (double)gb[e];
    }
    if (lane == 0) {
        double mx = part[0];
        #pragma unroll
        for (int e = 1; e < NEXP; e++) mx = fmax(mx, part[e]);
        double ex[NEXP]; double s = 0.0;
        #pragma unroll
        for (int e = 0; e < NEXP; e++) { ex[e] = exp(part[e] - mx); s += ex[e]; }
        int i0 = 0;
        #pragma unroll
        for (int e = 1; e < NEXP; e++) if (ex[e] > ex[i0]) i0 = e;   // first-max tie-break, matches top_k
        int i1 = (i0 == 0) ? 1 : 0;
        #pragma unroll
        for (int e = 0; e < NEXP; e++) if (e != i0 && ex[e] > ex[i1]) i1 = e;
        float g0 = (float)(ex[i0] / s), g1 = (float)(ex[i1] / s);
        float dn = g0 + g1 + 1e-9f;
        float w0 = g0 / dn, w1 = g1 / dn;
        int s0 = atomicAdd(&count[i0], 1);
        tok_list[i0 * N_TOK + s0] = n;  wt_list[i0 * N_TOK + s0] = w0;
        int s1 = atomicAdd(&count[i1], 1);
        tok_list[i1 * N_TOK + s1] = n;  wt_list[i1 * N_TOK + s1] = w1;
    }
}

// ---------------- tiny prefix scan over 8 expert counts ----------------
__global__ void scan_kernel(const int* __restrict__ count, int* __restrict__ basep) {
    if (threadIdx.x == 0) {
        int s = 0;
        for (int e = 0; e < NEXP; e++) { basep[e] = s; s += count[e]; }
    }
}

// ---------------- GEMM1: h = gelu(x_gathered @ w1[e] + b1[e]) ----------------
// 128x128 tile, BK=64 (12 K-steps instead of 24 -> half the latency-exposed
// barrier drains), 4 waves (2x2), 4x4 mfma_f32_16x16x32_f16 per wave, 2
// k-substeps per step. Serialized stage->barrier->compute loop (round-1
// structure: static LDS indices, plain __syncthreads, compiler-scheduled).
__global__ __launch_bounds__(256) void mm1_kernel(const _Float16* __restrict__ xh,
                                                  const _Float16* __restrict__ w1t,
                                                  const float* __restrict__ bias1,
                                                  const int* __restrict__ tok_list,
                                                  const int* __restrict__ count,
                                                  const int* __restrict__ basep,
                                                  _Float16* __restrict__ h) {
    const int e    = blockIdx.y;
    const int cnt  = count[e];
    const int row0 = blockIdx.z * 128;
    if (row0 >= cnt) return;
    const int col0 = blockIdx.x * 128;
    const int t    = threadIdx.x;
    const int lane = t & 63;
    const int wv   = t >> 6;
    const int wy   = wv >> 1, wx = wv & 1;
    const int m_lane = lane & 15, quad = lane >> 4;

    __shared__ __align__(16) _Float16 As[128][64];
    __shared__ __align__(16) _Float16 Bs[128][64];

    const int srow = t >> 3;            // 0..31 staging row within group
    const int kin  = (t & 7) * 8;       // 8-elem k chunk, 0..56

    // A: 4 row-groups of 32, gathered tokens
    const _Float16* pa[4];
    #pragma unroll
    for (int g = 0; g < 4; g++) {
        int i = row0 + g * 32 + srow; if (i > cnt - 1) i = cnt - 1;
        pa[g] = xh + (size_t)tok_list[e * N_TOK + i] * DIM + kin;
    }
    // B: 4 row-groups of 32 (w1t rows are k-contiguous)
    const _Float16* pb[4];
    #pragma unroll
    for (int g = 0; g < 4; g++)
        pb[g] = w1t + (size_t)e * FDIM * DIM + (size_t)(col0 + g * 32 + srow) * DIM + kin;

    f32x4 acc[4][4];
    #pragma unroll
    for (int i = 0; i < 4; i++)
        #pragma unroll
        for (int j = 0; j < 4; j++)
            acc[i][j] = (f32x4){0.f, 0.f, 0.f, 0.f};

    for (int kk = 0; kk < DIM; kk += 64) {      // 12 steps
        __syncthreads();                         // previous tile's reads done
        #pragma unroll
        for (int g = 0; g < 4; g++) gload_lds16(pa[g] + kk, &As[g * 32 + srow][kin]);
        #pragma unroll
        for (int g = 0; g < 4; g++) gload_lds16(pb[g] + kk, &Bs[g * 32 + srow][kin]);
        __syncthreads();                         // implicit vmcnt(0) drain
        #pragma unroll
        for (int ks = 0; ks < 2; ks++) {
            f16x8 af[4], bf[4];
            #pragma unroll
            for (int i = 0; i < 4; i++)
                af[i] = *(const f16x8*)&As[wy * 64 + i * 16 + m_lane][ks * 32 + quad * 8];
            #pragma unroll
            for (int j = 0; j < 4; j++)
                bf[j] = *(const f16x8*)&Bs[wx * 64 + j * 16 + m_lane][ks * 32 + quad * 8];
            #pragma unroll
            for (int i = 0; i < 4; i++)
                #pragma unroll
                for (int j = 0; j < 4; j++)
                    acc[i][j] = __builtin_amdgcn_mfma_f32_16x16x32_f16(af[i], bf[j], acc[i][j], 0, 0, 0);
        }
    }

    const int hbase = basep[e];
    #pragma unroll
    for (int i = 0; i < 4; i++) {
        #pragma unroll
        for (int r = 0; r < 4; r++) {
            int rl = wy * 64 + i * 16 + quad * 4 + r;   // C/D: row=(lane>>4)*4+reg
            int gr = row0 + rl;
            if (gr < cnt) {
                _Float16* hrow = h + (size_t)(hbase + gr) * FDIM;
                #pragma unroll
                for (int j = 0; j < 4; j++) {
                    int c = col0 + wx * 64 + j * 16 + m_lane;   // C/D: col=lane&15
                    float v = acc[i][j][r] + bias1[e * FDIM + c];
                    hrow[c] = (_Float16)gelu_exact(v);
                }
            }
        }
    }
}

// ---------------- GEMM2: out += gate_w * (h @ w2[e] + b2[e]) ----------------
// 64x128 tile (live blocks 384 -> 768, 3/CU: fixes grid starvation), BK=64
// (48 K-steps instead of 96). 4 waves, each owns 64 rows x 32 cols: acc[4][2],
// 16 MFMA per step. No split-K (round-3 post-mortem: it regressed).
__global__ __launch_bounds__(256) void mm2_kernel(const _Float16* __restrict__ h,
                                                  const _Float16* __restrict__ w2t,
                                                  const float* __restrict__ bias2,
                                                  const int* __restrict__ tok_list,
                                                  const float* __restrict__ wt_list,
                                                  const int* __restrict__ count,
                                                  const int* __restrict__ basep,
                                                  float* __restrict__ out) {
    const int e    = blockIdx.y;
    const int cnt  = count[e];
    const int row0 = blockIdx.z * 64;
    if (row0 >= cnt) return;
    const int col0 = blockIdx.x * 128;
    const int t    = threadIdx.x;
    const int lane = t & 63;
    const int wv   = t >> 6;            // wave -> 32-col group
    const int m_lane = lane & 15, quad = lane >> 4;

    __shared__ __align__(16) _Float16 As[64][64];
    __shared__ __align__(16) _Float16 Bs[128][64];

    const int srow = t >> 3;            // 0..31
    const int kin  = (t & 7) * 8;

    const int hbase = basep[e];
    const _Float16* pa[2];
    #pragma unroll
    for (int g = 0; g < 2; g++) {
        int i = row0 + g * 32 + srow; if (i > cnt - 1) i = cnt - 1;
        pa[g] = h + (size_t)(hbase + i) * FDIM + kin;
    }
    const _Float16* pb[4];
    #pragma unroll
    for (int g = 0; g < 4; g++)
        pb[g] = w2t + (size_t)e * DIM * FDIM + (size_t)(col0 + g * 32 + srow) * FDIM + kin;

    f32x4 acc[4][2];
    #pragma unroll
    for (int i = 0; i < 4; i++)
        #pragma unroll
        for (int j = 0; j < 2; j++)
            acc[i][j] = (f32x4){0.f, 0.f, 0.f, 0.f};

    for (int kk = 0; kk < FDIM; kk += 64) {     // 48 steps
        __syncthreads();
        #pragma unroll
        for (int g = 0; g < 2; g++) gload_lds16(pa[g] + kk, &As[g * 32 + srow][kin]);
        #pragma unroll
        for (int g = 0; g < 4; g++) gload_lds16(pb[g] + kk, &Bs[g * 32 + srow][kin]);
        __syncthreads();
        #pragma unroll
        for (int ks = 0; ks < 2; ks++) {
            f16x8 af[4], bf[2];
            #pragma unroll
            for (int i = 0; i < 4; i++)
                af[i] = *(const f16x8*)&As[i * 16 + m_lane][ks * 32 + quad * 8];
            #pragma unroll
            for (int j = 0; j < 2; j++)
                bf[j] = *(const f16x8*)&Bs[wv * 32 + j * 16 + m_lane][ks * 32 + quad * 8];
            #pragma unroll
            for (int i = 0; i < 4; i++)
                #pragma unroll
                for (int j = 0; j < 2; j++)
                    acc[i][j] = __builtin_amdgcn_mfma_f32_16x16x32_f16(af[i], bf[j], acc[i][j], 0, 0, 0);
        }
    }

    #pragma unroll
    for (int i = 0; i < 4; i++) {
        #pragma unroll
        for (int r = 0; r < 4; r++) {
            int rl = i * 16 + quad * 4 + r;         // 0..63
            int gr = row0 + rl;
            if (gr < cnt) {
                int tok   = tok_list[e * N_TOK + gr];
                float wgt = wt_list[e * N_TOK + gr];
                float* orow = out + (size_t)tok * DIM;
                #pragma unroll
                for (int j = 0; j < 2; j++) {
                    int c = col0 + wv * 32 + j * 16 + m_lane;
                    float v = acc[i][j][r] + bias2[e * DIM + c];
                    atomicAdd(&orow[c], wgt * v);
                }
            }
        }
    }
}

extern "C" void kernel_launch(void* const* d_in, const int* in_sizes, int n_in,
                              void* d_out, int out_size, void* d_ws, size_t ws_size,
                              hipStream_t stream) {
    const float* x  = (const float*)d_in[0];
    const float* gw = (const float*)d_in[1];
    const float* gb = (const float*)d_in[2];
    const float* w1 = (const float*)d_in[3];
    const float* b1 = (const float*)d_in[4];
    const float* w2 = (const float*)d_in[5];
    const float* b2 = (const float*)d_in[6];
    float* out = (float*)d_out;

    // workspace layout (all 16B-aligned); total ~132.4 MB
    char* ws = (char*)d_ws;
    _Float16* xh   = (_Float16*)ws;                                    // 4096*768
    _Float16* w1t  = xh  + (size_t)N_TOK * DIM;                        // [E][F][D]
    _Float16* w2t  = w1t + (size_t)NEXP * FDIM * DIM;                  // [E][D][F]
    _Float16* hbuf = w2t + (size_t)NEXP * DIM * FDIM;                  // [2N][F] compact slots
    int*   tok_list = (int*)(hbuf + (size_t)2 * N_TOK * FDIM);         // [E][N]
    float* wt_list  = (float*)(tok_list + NEXP * N_TOK);               // [E][N]
    int*   count    = (int*)(wt_list + NEXP * N_TOK);                  // [E]
    int*   basep    = count + 8;                                       // [E]

    hipMemsetAsync(count, 0, 64, stream);                 // count + base
    hipMemsetAsync(out, 0, (size_t)out_size * sizeof(float), stream);

    cast_x_kernel<<<dim3(N_TOK * DIM / 4 / 256), 256, 0, stream>>>(x, xh);
    // w1: [E][768][3072] -> w1t [E][3072][768]; w2: [E][3072][768] -> w2t [E][768][3072]
    transpose_cast2_kernel<<<dim3(576, 16), 256, 0, stream>>>(w1, w2, w1t, w2t);
    gate_kernel<<<dim3(N_TOK / 4), 256, 0, stream>>>(x, gw, gb, tok_list, wt_list, count);
    scan_kernel<<<1, 64, 0, stream>>>(count, basep);
    // grid: (cols, experts, rowblocks) -> live blocks are a dense prefix
    mm1_kernel<<<dim3(FDIM / 128, NEXP, N_TOK / 128), 256, 0, stream>>>(
        xh, w1t, b1, tok_list, count, basep, hbuf);
    mm2_kernel<<<dim3(DIM / 128, NEXP, N_TOK / 64), 256, 0, stream>>>(
        hbuf, w2t, b2, tok_list, wt_list, count, basep, out);
}

// Round 5
// 486.597 us; speedup vs baseline: 1.1441x; 1.0418x over previous
//
#include <hip/hip_runtime.h>
#include <hip/hip_bf16.h>

// MoE layer, routed top-2 implementation.
// N=4096 tokens, D=768, F=3072, E=8. All inputs fp32; compute in f16 MFMA
// (fp32 accumulate), gating in fp64 for exact top-2 selection.

#define N_TOK 4096
#define DIM   768
#define FDIM  3072
#define NEXP  8

typedef __attribute__((ext_vector_type(8))) _Float16 f16x8;
typedef __attribute__((ext_vector_type(4))) _Float16 f16x4;
typedef __attribute__((ext_vector_type(4))) float     f32x4;

__device__ __forceinline__ float gelu_exact(float v) {
    return 0.5f * v * (1.0f + erff(v * 0.7071067811865475f));
}

// async global->LDS, 16B per lane. Dest must be wave-uniform base + lane*16.
__device__ __forceinline__ void gload_lds16(const _Float16* g, _Float16* l) {
    __builtin_amdgcn_global_load_lds(
        (const __attribute__((address_space(1))) void*)g,
        (__attribute__((address_space(3))) void*)l,
        16, 0, 0);
}

// ---------------- cast x (fp32 -> f16), vectorized ----------------
__global__ __launch_bounds__(256) void cast_x_kernel(const float* __restrict__ x,
                                                     _Float16* __restrict__ xh) {
    int i = blockIdx.x * 256 + threadIdx.x;   // one float4 per thread, grid sized exactly
    float4 v = ((const float4*)x)[i];
    f16x4 o;
    o[0] = (_Float16)v.x; o[1] = (_Float16)v.y;
    o[2] = (_Float16)v.z; o[3] = (_Float16)v.w;
    ((f16x4*)xh)[i] = o;
}

// ---------------- merged transpose + cast for w1 and w2 ----------------
// fp32 [E][R][C] -> f16 [E][C][R]; blockIdx.y: 0..7 = w1 experts, 8..15 = w2.
__global__ __launch_bounds__(256) void transpose_cast2_kernel(const float* __restrict__ w1,
                                                              const float* __restrict__ w2,
                                                              _Float16* __restrict__ w1t,
                                                              _Float16* __restrict__ w2t) {
    const int z     = blockIdx.y;
    const int which = z >> 3;
    const int e     = z & 7;
    const float* in; _Float16* out; int R, C, tx, ty;
    if (which == 0) { in = w1; out = w1t; R = DIM;  C = FDIM; tx = blockIdx.x % (FDIM / 64); ty = blockIdx.x / (FDIM / 64); }
    else            { in = w2; out = w2t; R = FDIM; C = DIM;  tx = blockIdx.x % (DIM  / 64); ty = blockIdx.x / (DIM  / 64); }
    const size_t eoff = (size_t)e * R * C;
    const int c0 = tx * 64;
    const int r0 = ty * 64;
    __shared__ _Float16 tile[64][66];   // pitch 66 to soften bank conflicts
    const int t = threadIdx.x;
    #pragma unroll
    for (int it = 0; it < 4; it++) {
        int lin = it * 256 + t;
        int r  = lin >> 4;       // 0..63
        int c4 = lin & 15;       // float4 column group
        float4 v = *(const float4*)&in[eoff + (size_t)(r0 + r) * C + c0 + c4 * 4];
        tile[r][c4 * 4 + 0] = (_Float16)v.x;
        tile[r][c4 * 4 + 1] = (_Float16)v.y;
        tile[r][c4 * 4 + 2] = (_Float16)v.z;
        tile[r][c4 * 4 + 3] = (_Float16)v.w;
    }
    __syncthreads();
    #pragma unroll
    for (int it = 0; it < 4; it++) {
        int lin = it * 256 + t;
        int c  = lin >> 4;       // out row (= original column)
        int r4 = lin & 15;       // group of 4 original rows
        f16x4 o;
        #pragma unroll
        for (int j = 0; j < 4; j++) o[j] = tile[r4 * 4 + j][c];
        *(f16x4*)&out[eoff + (size_t)(c0 + c) * R + r0 + r4 * 4] = o;
    }
}

// ---------------- gating: fp64 logits, softmax, top-2, per-expert lists ----------------
__global__ __launch_bounds__(256) void gate_kernel(const float* __restrict__ x,
                                                   const float* __restrict__ gw,
                                                   const float* __restrict__ gb,
                                                   int* __restrict__ tok_list,
                                                   float* __restrict__ wt_list,
                                                   int* __restrict__ count) {
    const int gtid = blockIdx.x * 256 + threadIdx.x;
    const int n    = gtid >> 6;        // one wave per token
    const int lane = threadIdx.x & 63;
    if (n >= N_TOK) return;
    double part[NEXP];
    #pragma unroll
    for (int e = 0; e < NEXP; e++) part[e] = 0.0;
    for (int d = lane; d < DIM; d += 64) {
        float xv = x[n * DIM + d];
        const float* g = &gw[d * NEXP];
        #pragma unroll
        for (int e = 0; e < NEXP; e++) part[e] += (double)xv * (double)g[e];
    }
    #pragma unroll
    for (int e = 0; e < NEXP; e++) {
        double v = part[e];
        #pragma unroll
        for (int off = 32; off > 0; off >>= 1) v += __shfl_xor(v, off);
        part[e] = v + (double)gb[e];
    }
    if (lane == 0) {
        double mx = part[0];
        #pragma unroll
        for (int e = 1; e < NEXP; e++) mx = fmax(mx, part[e]);
        double ex[NEXP]; double s = 0.0;
        #pragma unroll
        for (int e = 0; e < NEXP; e++) { ex[e] = exp(part[e] - mx); s += ex[e]; }
        int i0 = 0;
        #pragma unroll
        for (int e = 1; e < NEXP; e++) if (ex[e] > ex[i0]) i0 = e;   // first-max tie-break, matches top_k
        int i1 = (i0 == 0) ? 1 : 0;
        #pragma unroll
        for (int e = 0; e < NEXP; e++) if (e != i0 && ex[e] > ex[i1]) i1 = e;
        float g0 = (float)(ex[i0] / s), g1 = (float)(ex[i1] / s);
        float dn = g0 + g1 + 1e-9f;
        float w0 = g0 / dn, w1 = g1 / dn;
        int s0 = atomicAdd(&count[i0], 1);
        tok_list[i0 * N_TOK + s0] = n;  wt_list[i0 * N_TOK + s0] = w0;
        int s1 = atomicAdd(&count[i1], 1);
        tok_list[i1 * N_TOK + s1] = n;  wt_list[i1 * N_TOK + s1] = w1;
    }
}

// ---------------- tiny prefix scan over 8 expert counts ----------------
__global__ void scan_kernel(const int* __restrict__ count, int* __restrict__ basep) {
    if (threadIdx.x == 0) {
        int s = 0;
        for (int e = 0; e < NEXP; e++) { basep[e] = s; s += count[e]; }
    }
}

// ---------------- GEMM1: h = gelu(x_gathered @ w1[e] + b1[e]) ----------------
// 128x128 tile, BK=64, 4 waves (2x2), 4x4 mfma_f32_16x16x32_f16, 2 k-substeps.
// LDS K-chunk XOR swizzle (T2, rule #21 both-sides): gload_lds dest stays
// LINEAR; the per-lane GLOBAL source chunk is pre-swizzled (c ^= row&7), and
// the ds_read column applies the same XOR. Kills the 16-way bank conflict of
// the 128-B-row layout (round-4: 15M conflict cycles) while preserving full
// coalescing (chunks permute within the same 128-B segment).
__global__ __launch_bounds__(256) void mm1_kernel(const _Float16* __restrict__ xh,
                                                  const _Float16* __restrict__ w1t,
                                                  const float* __restrict__ bias1,
                                                  const int* __restrict__ tok_list,
                                                  const int* __restrict__ count,
                                                  const int* __restrict__ basep,
                                                  _Float16* __restrict__ h) {
    const int e    = blockIdx.y;
    const int cnt  = count[e];
    const int row0 = blockIdx.z * 128;
    if (row0 >= cnt) return;
    const int col0 = blockIdx.x * 128;
    const int t    = threadIdx.x;
    const int lane = t & 63;
    const int wv   = t >> 6;
    const int wy   = wv >> 1, wx = wv & 1;
    const int m_lane = lane & 15, quad = lane >> 4;

    __shared__ __align__(16) _Float16 As[128][64];
    __shared__ __align__(16) _Float16 Bs[128][64];

    const int srow    = t >> 3;                       // 0..31 staging row within group
    const int kin     = (t & 7) * 8;                  // LDS dest chunk (linear, lane order)
    const int kin_src = ((t & 7) ^ (srow & 7)) * 8;   // swizzled global source chunk

    // A: 4 row-groups of 32, gathered tokens
    const _Float16* pa[4];
    #pragma unroll
    for (int g = 0; g < 4; g++) {
        int i = row0 + g * 32 + srow; if (i > cnt - 1) i = cnt - 1;
        pa[g] = xh + (size_t)tok_list[e * N_TOK + i] * DIM + kin_src;
    }
    // B: 4 row-groups of 32 (w1t rows are k-contiguous)
    const _Float16* pb[4];
    #pragma unroll
    for (int g = 0; g < 4; g++)
        pb[g] = w1t + (size_t)e * FDIM * DIM + (size_t)(col0 + g * 32 + srow) * DIM + kin_src;

    f32x4 acc[4][4];
    #pragma unroll
    for (int i = 0; i < 4; i++)
        #pragma unroll
        for (int j = 0; j < 4; j++)
            acc[i][j] = (f32x4){0.f, 0.f, 0.f, 0.f};

    const int rsw = (m_lane & 7);   // read-side XOR (row&7 == m_lane&7 for all fragment rows)

    for (int kk = 0; kk < DIM; kk += 64) {      // 12 steps
        __syncthreads();                         // previous tile's reads done
        #pragma unroll
        for (int g = 0; g < 4; g++) gload_lds16(pa[g] + kk, &As[g * 32 + srow][kin]);
        #pragma unroll
        for (int g = 0; g < 4; g++) gload_lds16(pb[g] + kk, &Bs[g * 32 + srow][kin]);
        __syncthreads();                         // implicit vmcnt(0) drain
        #pragma unroll
        for (int ks = 0; ks < 2; ks++) {
            const int rc = ((ks * 4 + quad) ^ rsw) * 8;   // swizzled read column
            f16x8 af[4], bf[4];
            #pragma unroll
            for (int i = 0; i < 4; i++)
                af[i] = *(const f16x8*)&As[wy * 64 + i * 16 + m_lane][rc];
            #pragma unroll
            for (int j = 0; j < 4; j++)
                bf[j] = *(const f16x8*)&Bs[wx * 64 + j * 16 + m_lane][rc];
            #pragma unroll
            for (int i = 0; i < 4; i++)
                #pragma unroll
                for (int j = 0; j < 4; j++)
                    acc[i][j] = __builtin_amdgcn_mfma_f32_16x16x32_f16(af[i], bf[j], acc[i][j], 0, 0, 0);
        }
    }

    const int hbase = basep[e];
    #pragma unroll
    for (int i = 0; i < 4; i++) {
        #pragma unroll
        for (int r = 0; r < 4; r++) {
            int rl = wy * 64 + i * 16 + quad * 4 + r;   // C/D: row=(lane>>4)*4+reg
            int gr = row0 + rl;
            if (gr < cnt) {
                _Float16* hrow = h + (size_t)(hbase + gr) * FDIM;
                #pragma unroll
                for (int j = 0; j < 4; j++) {
                    int c = col0 + wx * 64 + j * 16 + m_lane;   // C/D: col=lane&15
                    float v = acc[i][j][r] + bias1[e * FDIM + c];
                    hrow[c] = (_Float16)gelu_exact(v);
                }
            }
        }
    }
}

// ---------------- GEMM2: out += gate_w * (h @ w2[e] + b2[e]) ----------------
// 64x128 tile (768 live blocks, 3/CU), BK=64 (48 K-steps). 4 waves, each owns
// 64 rows x 32 cols: acc[4][2]. Same K-chunk XOR swizzle as mm1.
__global__ __launch_bounds__(256) void mm2_kernel(const _Float16* __restrict__ h,
                                                  const _Float16* __restrict__ w2t,
                                                  const float* __restrict__ bias2,
                                                  const int* __restrict__ tok_list,
                                                  const float* __restrict__ wt_list,
                                                  const int* __restrict__ count,
                                                  const int* __restrict__ basep,
                                                  float* __restrict__ out) {
    const int e    = blockIdx.y;
    const int cnt  = count[e];
    const int row0 = blockIdx.z * 64;
    if (row0 >= cnt) return;
    const int col0 = blockIdx.x * 128;
    const int t    = threadIdx.x;
    const int lane = t & 63;
    const int wv   = t >> 6;            // wave -> 32-col group
    const int m_lane = lane & 15, quad = lane >> 4;

    __shared__ __align__(16) _Float16 As[64][64];
    __shared__ __align__(16) _Float16 Bs[128][64];

    const int srow    = t >> 3;            // 0..31
    const int kin     = (t & 7) * 8;
    const int kin_src = ((t & 7) ^ (srow & 7)) * 8;

    const int hbase = basep[e];
    const _Float16* pa[2];
    #pragma unroll
    for (int g = 0; g < 2; g++) {
        int i = row0 + g * 32 + srow; if (i > cnt - 1) i = cnt - 1;
        pa[g] = h + (size_t)(hbase + i) * FDIM + kin_src;
    }
    const _Float16* pb[4];
    #pragma unroll
    for (int g = 0; g < 4; g++)
        pb[g] = w2t + (size_t)e * DIM * FDIM + (size_t)(col0 + g * 32 + srow) * FDIM + kin_src;

    f32x4 acc[4][2];
    #pragma unroll
    for (int i = 0; i < 4; i++)
        #pragma unroll
        for (int j = 0; j < 2; j++)
            acc[i][j] = (f32x4){0.f, 0.f, 0.f, 0.f};

    const int rsw = (m_lane & 7);

    for (int kk = 0; kk < FDIM; kk += 64) {     // 48 steps
        __syncthreads();
        #pragma unroll
        for (int g = 0; g < 2; g++) gload_lds16(pa[g] + kk, &As[g * 32 + srow][kin]);
        #pragma unroll
        for (int g = 0; g < 4; g++) gload_lds16(pb[g] + kk, &Bs[g * 32 + srow][kin]);
        __syncthreads();
        #pragma unroll
        for (int ks = 0; ks < 2; ks++) {
            const int rc = ((ks * 4 + quad) ^ rsw) * 8;
            f16x8 af[4], bf[2];
            #pragma unroll
            for (int i = 0; i < 4; i++)
                af[i] = *(const f16x8*)&As[i * 16 + m_lane][rc];
            #pragma unroll
            for (int j = 0; j < 2; j++)
                bf[j] = *(const f16x8*)&Bs[wv * 32 + j * 16 + m_lane][rc];
            #pragma unroll
            for (int i = 0; i < 4; i++)
                #pragma unroll
                for (int j = 0; j < 2; j++)
                    acc[i][j] = __builtin_amdgcn_mfma_f32_16x16x32_f16(af[i], bf[j], acc[i][j], 0, 0, 0);
        }
    }

    #pragma unroll
    for (int i = 0; i < 4; i++) {
        #pragma unroll
        for (int r = 0; r < 4; r++) {
            int rl = i * 16 + quad * 4 + r;         // 0..63
            int gr = row0 + rl;
            if (gr < cnt) {
                int tok   = tok_list[e * N_TOK + gr];
                float wgt = wt_list[e * N_TOK + gr];
                float* orow = out + (size_t)tok * DIM;
                #pragma unroll
                for (int j = 0; j < 2; j++) {
                    int c = col0 + wv * 32 + j * 16 + m_lane;
                    float v = acc[i][j][r] + bias2[e * DIM + c];
                    atomicAdd(&orow[c], wgt * v);
                }
            }
        }
    }
}

extern "C" void kernel_launch(void* const* d_in, const int* in_sizes, int n_in,
                              void* d_out, int out_size, void* d_ws, size_t ws_size,
                              hipStream_t stream) {
    const float* x  = (const float*)d_in[0];
    const float* gw = (const float*)d_in[1];
    const float* gb = (const float*)d_in[2];
    const float* w1 = (const float*)d_in[3];
    const float* b1 = (const float*)d_in[4];
    const float* w2 = (const float*)d_in[5];
    const float* b2 = (const float*)d_in[6];
    float* out = (float*)d_out;

    // workspace layout (all 16B-aligned); total ~132.4 MB
    char* ws = (char*)d_ws;
    _Float16* xh   = (_Float16*)ws;                                    // 4096*768
    _Float16* w1t  = xh  + (size_t)N_TOK * DIM;                        // [E][F][D]
    _Float16* w2t  = w1t + (size_t)NEXP * FDIM * DIM;                  // [E][D][F]
    _Float16* hbuf = w2t + (size_t)NEXP * DIM * FDIM;                  // [2N][F] compact slots
    int*   tok_list = (int*)(hbuf + (size_t)2 * N_TOK * FDIM);         // [E][N]
    float* wt_list  = (float*)(tok_list + NEXP * N_TOK);               // [E][N]
    int*   count    = (int*)(wt_list + NEXP * N_TOK);                  // [E]
    int*   basep    = count + 8;                                       // [E]

    hipMemsetAsync(count, 0, 64, stream);                 // count + base
    hipMemsetAsync(out, 0, (size_t)out_size * sizeof(float), stream);

    cast_x_kernel<<<dim3(N_TOK * DIM / 4 / 256), 256, 0, stream>>>(x, xh);
    // w1: [E][768][3072] -> w1t [E][3072][768]; w2: [E][3072][768] -> w2t [E][768][3072]
    transpose_cast2_kernel<<<dim3(576, 16), 256, 0, stream>>>(w1, w2, w1t, w2t);
    gate_kernel<<<dim3(N_TOK / 4), 256, 0, stream>>>(x, gw, gb, tok_list, wt_list, count);
    scan_kernel<<<1, 64, 0, stream>>>(count, basep);
    // grid: (cols, experts, rowblocks) -> live blocks are a dense prefix
    mm1_kernel<<<dim3(FDIM / 128, NEXP, N_TOK / 128), 256, 0, stream>>>(
        xh, w1t, b1, tok_list, count, basep, hbuf);
    mm2_kernel<<<dim3(DIM / 128, NEXP, N_TOK / 64), 256, 0, stream>>>(
        hbuf, w2t, b2, tok_list, wt_list, count, basep, out);
}